// Round 7
// baseline (133.474 us; speedup 1.0000x reference)
//
#include <hip/hip_runtime.h>
#include <math.h>

// B,S,D,V,N_BLOCKS = 4096,128,9,5,4
constexpr int Bn = 4096;
constexpr int Sn = 128;
constexpr int Dn = 9;
constexpr int Vn = 5;
constexpr int NBn = 4;

typedef float f4 __attribute__((ext_vector_type(4)));
typedef _Float16 h8 __attribute__((ext_vector_type(8)));   // MFMA operand type
typedef __fp16   h2 __attribute__((ext_vector_type(2)));
typedef unsigned u4v __attribute__((ext_vector_type(4)));
typedef short s4v __attribute__((ext_vector_type(4)));

// Workspace layout (floats):
//  [it*96 + e*9 + d]  = M'[e][d] = qscale * sum_f Wk[f][e]*Wq[f][d]   (it<4, e,d<9)
//  [it*96 + 81 + d]   = w'[d]    = qscale * sum_f Wk[f][d]*bq[f]
//  [384 + r*9 + d]    = positional encoding PE[r][d]
// Softmax shift invariance: S[q][k] = x_q M x_k + w.x_k (+ per-q consts that
// cancel), so K-side needs NO projection and bk drops out entirely.
constexpr int WS_PE = 384;

// R6 POST-MORTEM: occupancy 36->70% bought nothing (62.2 -> 64.8us) because
// the limiter is the per-CU LDS pipe (128B/clk shared by 4 SIMDs): the
// 8-wave/1-tile layout made every wave re-read all 8 KF tiles (LDS-op count
// and SQ_LDS_BANK_CONFLICT exactly doubled vs the 4-wave/2-tile layout).
// R7: DUAL-BATCH block — two independent batches per 512-thread block, each
// half using R3's proven 4-wave x 2-q-tile structure (kfr read once per
// wave, reused for both tiles) and its own 30976B LDS slice.
//   -> 2 blocks/CU x 16 waves = 32 waves/CU (slot cap) for latency hiding,
//      with per-batch LDS traffic identical to R3 (~27% LDS-pipe busy).
//
// Per-half LDS layout (bytes), stride 80B rows (20 banks, odd multiple of 4;
// 8 lanes per 4-bank group = b128 minimum, zero excess conflict):
//  KF [128] rows x 32 fp16 slots [Xh(9)|Xh(9)|Xl(9)|th,tl|z3], stride 40 shorts
//  QF [128] rows x 32 fp16 slots [Yh(9)|Yl(9)|Yh(9)|1,1|z3], Y = M'^T-proj of x
//     One K=32 MFMA yields Xh*Yh + Xh*Yl + Xl*Yh + t (exact to ~2^-22).
//  VF [16][136] fp16 V^T; row 9 = 1.0 (written once) so the PV MFMA also
//     produces the softmax denominator as O^T row 9. Rows 10..15 unwritten.
//  XB [128][12] f32 inter-layer activations, stride 48B
// No-max softmax: scores bounded |s|<~12 in log2 domain; exp2 direct is safe
// (fp16 max 2^15.99) and rcp-normalization restores the exact softmax.
constexpr int KF_OFF = 0;          // 10240
constexpr int QF_OFF = 10240;      // 10240
constexpr int VF_OFF = 20480;      // 16*272 = 4352
constexpr int XB_OFF = 24832;      // 6144
constexpr int SMEM_HALF = 30976;
constexpr int SMEM_BYTES = 2 * SMEM_HALF;   // 61952 <= 64KB

static __device__ __forceinline__ void split_hl(const float* v, _Float16* H, _Float16* L) {
    #pragma unroll
    for (int i = 0; i < 9; ++i) {
        _Float16 h = (_Float16)v[i];
        H[i] = h;
        L[i] = (_Float16)(v[i] - (float)h);
    }
}

static __device__ __forceinline__ unsigned pk(_Float16 a, _Float16 b) {
    h2 t; t.x = (__fp16)a; t.y = (__fp16)b;
    return __builtin_bit_cast(unsigned, t);
}

// Store one 32-slot row [X(9)|Y(9)|Z(9)|T0,T1|0,0,0] (4 x b128)
static __device__ __forceinline__ void store_row32(short* rowp,
        const _Float16* X, const _Float16* Y, const _Float16* Z,
        _Float16 T0, _Float16 T1) {
    const _Float16 z0 = (_Float16)0.0f;
    u4v w0 = (u4v){ pk(X[0],X[1]), pk(X[2],X[3]), pk(X[4],X[5]), pk(X[6],X[7]) };
    u4v w1 = (u4v){ pk(X[8],Y[0]), pk(Y[1],Y[2]), pk(Y[3],Y[4]), pk(Y[5],Y[6]) };
    u4v w2 = (u4v){ pk(Y[7],Y[8]), pk(Z[0],Z[1]), pk(Z[2],Z[3]), pk(Z[4],Z[5]) };
    u4v w3 = (u4v){ pk(Z[6],Z[7]), pk(Z[8],T0),   pk(T1,z0),     0u            };
    u4v* qp = (u4v*)rowp;
    qp[0] = w0; qp[1] = w1; qp[2] = w2; qp[3] = w3;
}

static __device__ __forceinline__ h8 read_quad(const short* base, int row, int quad) {
    return *(const h8*)(base + row * 40 + quad * 8);
}

// Tiny prep: M'/w' folds (input-only, shared by all blocks) + PE table.
__global__ void prep_kernel(const float* __restrict__ Wq, const float* __restrict__ bq,
                            const float* __restrict__ Wk, float* __restrict__ ws)
{
    const float qs = (1.0f / 3.0f) * 1.44269504f;   // 1/sqrt(D) * log2(e)
    const int idx = blockIdx.x * 256 + threadIdx.x;
    if (idx < 360) {
        const int it = idx / 90, j = idx % 90;
        const float* wq = Wq + it * 81;
        const float* wk = Wk + it * 81;
        float acc = 0.0f;
        if (j < 81) {
            const int e = j / 9, d = j % 9;
            #pragma unroll
            for (int f = 0; f < 9; ++f) acc = fmaf(wk[f * 9 + e], wq[f * 9 + d], acc);
        } else {
            const int d = j - 81;
            const float* bqp = bq + it * 9;
            #pragma unroll
            for (int f = 0; f < 9; ++f) acc = fmaf(wk[f * 9 + d], bqp[f], acc);
        }
        ws[it * 96 + j] = acc * qs;
    } else if (idx < 360 + Sn * Dn) {
        const int j = idx - 360;
        const int r = j / 9, d = j % 9;
        const float inv_freq[Dn] = {
            1.0f, 1.0f, 0.1291549665f, 0.1291549665f, 0.0166810054f,
            0.0166810054f, 0.0021544347f, 0.0021544347f, 0.0002782559f };
        const float a = (float)r * inv_freq[d];
        ws[WS_PE + j] = (d & 1) ? cosf(a) : sinf(a);
    }
}

// One block = TWO batches. Half h = tid>>8 handles batch 2*blockIdx+h with
// threads tid8 = tid&255 in R3's structure: tid8<128 projects K (raw X rows
// + bias fold t) + V[0:4), tid8>=128 projects Y = M'^T x + V[4:9). Wave
// wq = (tid8>>6) owns q-tiles {2wq, 2wq+1}: S^T via one 3-term MFMA per
// key-tile, exp2 direct (no max), denominator from the PV ones-row,
// O^T = V^T.P^T fp16 (4 MFMAs).
__global__ __launch_bounds__(512, 8) void bert_kernel(
    const int*   __restrict__ tokens,
    const float* __restrict__ emb,
    const float* __restrict__ Wv, const float* __restrict__ bv,
    const float* __restrict__ Wout, const float* __restrict__ bout,
    const float* __restrict__ wsp,
    float*       __restrict__ out)
{
    __shared__ __align__(16) char smem[SMEM_BYTES];
    const int tid  = threadIdx.x;        // 0..511
    const int half = tid >> 8;           // 0/1: which batch of the pair
    const int tid8 = tid & 255;          // R3-style thread id within half
    char* base = smem + half * SMEM_HALF;
    short* KF = (short*)(base + KF_OFF);
    short* QF = (short*)(base + QF_OFF);
    short* VF = (short*)(base + VF_OFF);
    float* XB = (float*)(base + XB_OFF);

    const int bb  = blockIdx.x * 2 + half;   // batch index
    const int t   = tid8 & 63;
    const int wq  = tid8 >> 6;           // wave-within-half 0..3
    const int col = t & 15;
    const int g   = t >> 4;
    const bool lowhalf = tid8 < 128;
    const int r = tid8 & 127;            // staging row
    const float* MP = wsp;               // [4][96] M'/w'
    const float* PE = wsp + WS_PE;       // [128][9]

    // ---- stage 0: embed + positional encoding -> XB; VF ones row ----
    if (lowhalf) {
        const int tok = tokens[bb * Sn + r];
        float xr[9];
        #pragma unroll
        for (int d = 0; d < Dn; ++d)
            xr[d] = emb[tok * Dn + d] + PE[r * 9 + d];
        f4* xp = (f4*)&XB[r * 12];
        xp[0] = (f4){xr[0], xr[1], xr[2], xr[3]};
        xp[1] = (f4){xr[4], xr[5], xr[6], xr[7]};
        xp[2] = (f4){xr[8], 0.0f, 0.0f, 0.0f};
    } else {
        VF[9 * 136 + r] = (short)0x3C00;   // fp16 1.0 — persists across layers
    }
    __syncthreads();

    #pragma unroll 1
    for (int it = 0; it < NBn; ++it) {
        // ---- phase 1: staging (K side raw, Q side folded-projection) ----
        {
            const f4* xp = (const f4*)&XB[r * 12];
            f4 a0 = xp[0], a1 = xp[1], a2 = xp[2];
            float x[9] = {a0.x, a0.y, a0.z, a0.w, a1.x, a1.y, a1.z, a1.w, a2.x};
            const float* wv  = Wv + it * 81;
            const float* bvi = bv + it * 9;
            const float* mp  = MP + it * 96;
            if (lowhalf) {
                float tb = 0.0f;                      // t_k = w'.x (bias fold)
                #pragma unroll
                for (int d = 0; d < Dn; ++d) tb = fmaf(x[d], mp[81 + d], tb);
                _Float16 H[9], L[9];
                split_hl(x, H, L);
                _Float16 th = (_Float16)tb;
                _Float16 tl = (_Float16)(tb - (float)th);
                store_row32(KF + r * 40, H, H, L, th, tl);   // [Xh|Xh|Xl|th,tl]
                #pragma unroll
                for (int e = 0; e < 4; ++e) {
                    float av = bvi[e];
                    #pragma unroll
                    for (int d = 0; d < Dn; ++d) av = fmaf(x[d], wv[e * 9 + d], av);
                    VF[e * 136 + r] = __builtin_bit_cast(short, (_Float16)av);
                }
            } else {
                float y[9];                           // y = M'^T-fold of x (pre-scaled)
                #pragma unroll
                for (int e = 0; e < Dn; ++e) {
                    float a = 0.0f;
                    #pragma unroll
                    for (int d = 0; d < Dn; ++d) a = fmaf(x[d], mp[e * 9 + d], a);
                    y[e] = a;
                }
                _Float16 H[9], L[9];
                split_hl(y, H, L);
                store_row32(QF + r * 40, H, L, H,
                            (_Float16)1.0f, (_Float16)1.0f);  // [Yh|Yl|Yh|1,1]
                #pragma unroll
                for (int e = 4; e < Dn; ++e) {
                    float av = bvi[e];
                    #pragma unroll
                    for (int d = 0; d < Dn; ++d) av = fmaf(x[d], wv[e * 9 + d], av);
                    VF[e * 136 + r] = __builtin_bit_cast(short, (_Float16)av);
                }
            }
        }
        __syncthreads();

        // ---- phase 2: wave wq owns q-tiles 2wq, 2wq+1 ----
        h8 kfr[8];
        #pragma unroll
        for (int kt = 0; kt < 8; ++kt)
            kfr[kt] = read_quad(KF, kt * 16 + col, g);

        // V^T A-frags with permuted K-dim: slot (g,j) <-> key 16*(2s+(j>>2))+4g+(j&3)
        h8 vf[4];
        #pragma unroll
        for (int s = 0; s < 4; ++s) {
            const short* p0 = VF + col * 136 + 32 * s + 4 * g;
            s4v va = *(const s4v*)p0;
            s4v vb = *(const s4v*)(p0 + 16);
            vf[s] = __builtin_bit_cast(h8,
                __builtin_shufflevector(va, vb, 0, 1, 2, 3, 4, 5, 6, 7));
        }

        #pragma unroll
        for (int ti = 0; ti < 2; ++ti) {
            const int qt = 2 * wq + ti;
            const int q  = qt * 16 + col;
            h8 bq3 = read_quad(QF, q, g);

            f4 acc[8];
            #pragma unroll
            for (int kt = 0; kt < 8; ++kt)
                acc[kt] = __builtin_amdgcn_mfma_f32_16x16x32_f16(kfr[kt], bq3, (f4)(0.0f), 0, 0, 0);

            // lane holds S^T[key = kt*16 + 4g + rr][q] (log2 domain); exp2 direct.
            #pragma unroll
            for (int kt = 0; kt < 8; ++kt)
                #pragma unroll
                for (int rr = 0; rr < 4; ++rr)
                    acc[kt][rr] = __builtin_amdgcn_exp2f(acc[kt][rr]);

            // P B-frags: slot j=0..3 -> (kt=2s, rr=j); j=4..7 -> (kt=2s+1, rr=j&3)
            f4 oac = (f4)(0.0f);
            #pragma unroll
            for (int s = 0; s < 4; ++s) {
                u4v up = (u4v){
                    __builtin_bit_cast(unsigned, __builtin_amdgcn_cvt_pkrtz(acc[2*s][0],   acc[2*s][1])),
                    __builtin_bit_cast(unsigned, __builtin_amdgcn_cvt_pkrtz(acc[2*s][2],   acc[2*s][3])),
                    __builtin_bit_cast(unsigned, __builtin_amdgcn_cvt_pkrtz(acc[2*s+1][0], acc[2*s+1][1])),
                    __builtin_bit_cast(unsigned, __builtin_amdgcn_cvt_pkrtz(acc[2*s+1][2], acc[2*s+1][3])) };
                oac = __builtin_amdgcn_mfma_f32_16x16x32_f16(vf[s], __builtin_bit_cast(h8, up), oac, 0, 0, 0);
            }
            // denominator: O^T row 9 = sum_k P[k][q], held by lane 32+q, reg 1
            const float sm = __shfl(oac[1], 32 + col);
            const float rl = __builtin_amdgcn_rcpf(sm);
            oac *= rl;
            // O^T C-layout: lane col = q, rows d = 4g + rr; keep d < 12
            if (g < 3)
                *(f4*)&XB[q * 12 + g * 4] = oac;
        }
        __syncthreads();
    }

    // ---- logits + log_softmax ----
    if (lowhalf) {
        const f4* xp = (const f4*)&XB[r * 12];
        f4 a0 = xp[0], a1 = xp[1], a2 = xp[2];
        float xr[9] = {a0.x, a0.y, a0.z, a0.w, a1.x, a1.y, a1.z, a1.w, a2.x};
        float lg[Vn];
        #pragma unroll
        for (int v = 0; v < Vn; ++v) {
            float a = bout[v];
            #pragma unroll
            for (int d = 0; d < Dn; ++d) a = fmaf(xr[d], Wout[v * Dn + d], a);
            lg[v] = a;
        }
        float mm = lg[0];
        #pragma unroll
        for (int v = 1; v < Vn; ++v) mm = fmaxf(mm, lg[v]);
        float sum = 0.0f;
        #pragma unroll
        for (int v = 0; v < Vn; ++v)
            sum += __builtin_amdgcn_exp2f((lg[v] - mm) * 1.44269504f);
        const float lse = __builtin_amdgcn_logf(sum) * 0.69314718f + mm;
        float* op = out + ((size_t)bb * Sn + r) * Vn;
        #pragma unroll
        for (int v = 0; v < Vn; ++v) op[v] = lg[v] - lse;
    }
}

extern "C" void kernel_launch(void* const* d_in, const int* in_sizes, int n_in,
                              void* d_out, int out_size, void* d_ws, size_t ws_size,
                              hipStream_t stream) {
    const int*   tokens = (const int*)  d_in[0];
    const float* emb    = (const float*)d_in[1];
    const float* Wq     = (const float*)d_in[2];
    const float* bq_    = (const float*)d_in[3];
    const float* Wk     = (const float*)d_in[4];
    const float* Wv     = (const float*)d_in[6];
    const float* bv_    = (const float*)d_in[7];
    const float* Wout   = (const float*)d_in[8];
    const float* bout_  = (const float*)d_in[9];
    float* out = (float*)d_out;
    float* ws  = (float*)d_ws;

    prep_kernel<<<dim3(6), dim3(256), 0, stream>>>(Wq, bq_, Wk, ws);
    bert_kernel<<<dim3(Bn / 2), dim3(512), 0, stream>>>(
        tokens, emb, Wv, bv_, Wout, bout_, ws, out);
}

// Round 8
// 128.915 us; speedup vs baseline: 1.0354x; 1.0354x over previous
//
#include <hip/hip_runtime.h>
#include <math.h>

// B,S,D,V,N_BLOCKS = 4096,128,9,5,4
constexpr int Bn = 4096;
constexpr int Sn = 128;
constexpr int Dn = 9;
constexpr int Vn = 5;
constexpr int NBn = 4;

typedef float f4 __attribute__((ext_vector_type(4)));
typedef _Float16 h8 __attribute__((ext_vector_type(8)));   // MFMA operand type
typedef __fp16   h2 __attribute__((ext_vector_type(2)));
typedef unsigned u4v __attribute__((ext_vector_type(4)));
typedef short s4v __attribute__((ext_vector_type(4)));

// Workspace layout:
//  floats [it*96 + e*9 + d] = M'[e][d] = qs * sum_f Wk[f][e]*Wq[f][d]
//  floats [it*96 + 81 + d]  = w'[d]   = qs * sum_f Wk[f][d]*bq[f]
//  floats [384 .. 1536)     = PE[r][d] positional encoding
//  bytes  [6144 .. 14336)   = fp16 MFMA A-fragment table (prep2):
//     [it][op][e][s] halves, idx = it*1024 + op*512 + e*32 + s
//     op0 (Y-proj): rows e<9 = [Mh(9)|Mh(9)|Ml(9)|0^5]; e=9 = [wh|wh|wl|0^5]
//     op1 (V-proj): rows e<9 = [Wvh|Wvh|Wvl|0|0|0|bvh,bvl]; else 0
// Softmax shift invariance: S[q][k] = x_q M x_k + w'.x_k (+ per-q consts that
// cancel), so K-side needs NO projection and bk drops out entirely.
constexpr int WS_PE = 384;
constexpr int WS_FRAG_BYTES = 6144;

// R7 POST-MORTEM: VALU-issue time is ~35us across ALL structures (R3/R6/R7)
// while VALUBusy is pinned at 50-57% regardless of occupancy (36-70%) ->
// occupancy knobs exhausted; the floor is VALU instruction count.
// R8: MFMA-IZE THE PROJECTIONS. KF rows already hold X in MFMA fragment
// form, so Y = M'x (81 FMA/thread) and V = Wv x + bv (81 FMA spread) become
// 2 MFMAs per 16-row tile consuming KF as the B-operand; t = w'.x is row
// e=9 of the Y operand, and bv rides slots 30/31 against constant 1,1 in KF.
// Per layer: (a) all threads split-stage KF (2 threads/row, word-split),
// (b) waves run Y/V MFMAs (Y -> XB via the O-write pattern, V^T -> VF),
// (c) 2 threads/row build QF from Y + write th/tl into KF word 14,
// (d) attention unchanged.
//
// LDS layout (stride 80B rows = 20 banks, odd multiple of 4):
//  KF [128]x32 fp16 [Xh(9)|Xl(9)|Xh(9)|0,th,tl,1,1], stride 40 shorts
//  QF [128]x32 fp16 [Yh(9)|Yh(9)|Yl(9)|0,1,1,0,0]
//    QK pairing: XhYh + XlYh + XhYl + th + tl  (exact to ~2^-22)
//  VF [16][136] fp16 V^T; row 9 = 1.0 (ones for softmax denom; V-MFMA only
//    writes e<9). Rows 10..15 unwritten.
//  XB [128][12] f32: holds x, then Y (+t at col 9) mid-layer, then O.
// No-max softmax: scores bounded |s|<~12 in log2 domain; exp2 direct is safe
// (fp16 max 2^15.99) and rcp-normalization restores the exact softmax.
constexpr int KF_OFF = 0;          // 10240
constexpr int QF_OFF = 10240;      // 10240
constexpr int VF_OFF = 20480;      // 16*272 = 4352
constexpr int XB_OFF = 24832;      // 6144
constexpr int SMEM_BYTES = 30976;

static __device__ __forceinline__ unsigned pk(_Float16 a, _Float16 b) {
    h2 t; t.x = (__fp16)a; t.y = (__fp16)b;
    return __builtin_bit_cast(unsigned, t);
}

static __device__ __forceinline__ h8 read_quad(const short* base, int row, int quad) {
    return *(const h8*)(base + row * 40 + quad * 8);
}

// prep1: M'/w' folds + PE table (input-only, shared by all blocks).
__global__ void prep_kernel(const float* __restrict__ Wq, const float* __restrict__ bq,
                            const float* __restrict__ Wk, float* __restrict__ ws)
{
    const float qs = (1.0f / 3.0f) * 1.44269504f;   // 1/sqrt(D) * log2(e)
    const int idx = blockIdx.x * 256 + threadIdx.x;
    if (idx < 360) {
        const int it = idx / 90, j = idx % 90;
        const float* wq = Wq + it * 81;
        const float* wk = Wk + it * 81;
        float acc = 0.0f;
        if (j < 81) {
            const int e = j / 9, d = j % 9;
            #pragma unroll
            for (int f = 0; f < 9; ++f) acc = fmaf(wk[f * 9 + e], wq[f * 9 + d], acc);
        } else {
            const int d = j - 81;
            const float* bqp = bq + it * 9;
            #pragma unroll
            for (int f = 0; f < 9; ++f) acc = fmaf(wk[f * 9 + d], bqp[f], acc);
        }
        ws[it * 96 + j] = acc * qs;
    } else if (idx < 360 + Sn * Dn) {
        const int j = idx - 360;
        const int r = j / 9, d = j % 9;
        const float inv_freq[Dn] = {
            1.0f, 1.0f, 0.1291549665f, 0.1291549665f, 0.0166810054f,
            0.0166810054f, 0.0021544347f, 0.0021544347f, 0.0002782559f };
        const float a = (float)r * inv_freq[d];
        ws[WS_PE + j] = (d & 1) ? cosf(a) : sinf(a);
    }
}

// prep2: fp16 A-fragment table for the Y/V projection MFMAs (reads M'/w'
// from ws — separate launch after prep1 guarantees ordering).
__global__ void prep2_kernel(const float* __restrict__ Wv, const float* __restrict__ bv,
                             float* __restrict__ ws)
{
    const int idx = blockIdx.x * 256 + threadIdx.x;
    if (idx >= 4096) return;
    const int it = idx >> 10, rem = idx & 1023, op = rem >> 9;
    const int e = (rem >> 5) & 15, s = rem & 31;
    float v = 0.0f;
    bool lo = false;
    if (s < 27) {
        const int d = (s < 9) ? s : (s < 18 ? s - 9 : s - 18);
        lo = (s >= 18);
        if (op == 0) {
            if (e < 9)       v = ws[it * 96 + e * 9 + d];
            else if (e == 9) v = ws[it * 96 + 81 + d];
        } else {
            if (e < 9)       v = Wv[it * 81 + e * 9 + d];
        }
    } else if (op == 1 && e < 9 && s >= 30) {
        v = bv[it * 9 + e];          // bias hi/lo at slots 30/31 (pairs with 1,1 in KF)
        lo = (s == 31);
    }
    const _Float16 h = (_Float16)v;
    const _Float16 r = lo ? (_Float16)(v - (float)h) : h;
    ((_Float16*)((char*)ws + WS_FRAG_BYTES))[idx] = r;
}

// One block = one batch, 4 waves (R3 structure — best measured).
__global__ __launch_bounds__(256, 4) void bert_kernel(
    const int*   __restrict__ tokens,
    const float* __restrict__ emb,
    const float* __restrict__ Wout, const float* __restrict__ bout,
    const float* __restrict__ wsp,
    float*       __restrict__ out)
{
    __shared__ __align__(16) char smem[SMEM_BYTES];
    short* KF = (short*)(smem + KF_OFF);
    short* QF = (short*)(smem + QF_OFF);
    short* VF = (short*)(smem + VF_OFF);
    float* XB = (float*)(smem + XB_OFF);

    const int b   = blockIdx.x;
    const int tid = threadIdx.x;         // 0..255
    const int t   = tid & 63;
    const int wv  = tid >> 6;            // wave 0..3
    const int col = t & 15;
    const int g   = t >> 4;
    const bool hi = tid >= 128;
    const int r = tid & 127;             // staging row
    const float* PE = wsp + WS_PE;       // [128][9]
    const _Float16* FB = (const _Float16*)((const char*)wsp + WS_FRAG_BYTES);
    const _Float16 one = (_Float16)1.0f;
    const _Float16 z0  = (_Float16)0.0f;

    // ---- stage 0: embed + positional encoding -> XB; VF ones row ----
    if (!hi) {
        const int tok = tokens[b * Sn + r];
        float xr[9];
        #pragma unroll
        for (int d = 0; d < Dn; ++d)
            xr[d] = emb[tok * Dn + d] + PE[r * 9 + d];
        f4* xp = (f4*)&XB[r * 12];
        xp[0] = (f4){xr[0], xr[1], xr[2], xr[3]};
        xp[1] = (f4){xr[4], xr[5], xr[6], xr[7]};
        xp[2] = (f4){xr[8], 0.0f, 0.0f, 0.0f};
    } else {
        VF[9 * 136 + r] = (short)0x3C00;   // fp16 1.0 — persists across layers
    }
    __syncthreads();

    #pragma unroll 1
    for (int it = 0; it < NBn; ++it) {
        // A-frags for this layer (L2-hot; issued early, consumed in (b))
        const _Float16* fb = FB + it * 1024;
        const h8 aM = *(const h8*)(fb + col * 32 + g * 8);
        const h8 aV = *(const h8*)(fb + 512 + col * 32 + g * 8);

        // ---- (a): stage KF rows, 2 threads per row (word-split) ----
        {
            const f4* xp = (const f4*)&XB[r * 12];
            f4 a0 = xp[0], a1 = xp[1], a2 = xp[2];
            float x[9] = {a0.x, a0.y, a0.z, a0.w, a1.x, a1.y, a1.z, a1.w, a2.x};
            _Float16 H[9];
            #pragma unroll
            for (int d = 0; d < Dn; ++d) H[d] = (_Float16)x[d];
            u4v* qp = (u4v*)(KF + r * 40);
            if (!hi) {
                const _Float16 l7 = (_Float16)(x[7] - (float)H[7]);
                const _Float16 l8 = (_Float16)(x[8] - (float)H[8]);
                qp[0] = (u4v){ pk(H[0],H[1]), pk(H[2],H[3]), pk(H[4],H[5]), pk(H[6],H[7]) };
                qp[2] = (u4v){ pk(l7,l8),     pk(H[0],H[1]), pk(H[2],H[3]), pk(H[4],H[5]) };
            } else {
                _Float16 l[7];
                #pragma unroll
                for (int d = 0; d < 7; ++d) l[d] = (_Float16)(x[d] - (float)H[d]);
                qp[1] = (u4v){ pk(H[8],l[0]), pk(l[1],l[2]), pk(l[3],l[4]), pk(l[5],l[6]) };
                // slots 24-31: Xh6,Xh7,Xh8, 0, th,tl (placeholder 0), 1,1
                qp[3] = (u4v){ pk(H[6],H[7]), pk(H[8],z0), 0u, pk(one,one) };
            }
        }
        __syncthreads();

        // ---- (b): Y = M''.x and V = Wv''.x via MFMA (B-operand = KF) ----
        #pragma unroll
        for (int sub = 0; sub < 2; ++sub) {
            const int xrow = (2 * wv + sub) * 16 + col;
            h8 bx = read_quad(KF, xrow, g);
            f4 yD = __builtin_amdgcn_mfma_f32_16x16x32_f16(aM, bx, (f4)(0.0f), 0, 0, 0);
            f4 vD = __builtin_amdgcn_mfma_f32_16x16x32_f16(aV, bx, (f4)(0.0f), 0, 0, 0);
            // D: col=lane&15 -> x-row, row=4g+rr -> e. Y rows 0..8 + t at e=9.
            if (g < 3) *(f4*)&XB[xrow * 12 + g * 4] = yD;
            #pragma unroll
            for (int rr = 0; rr < 4; ++rr) {
                const int e = 4 * g + rr;
                if (e < 9)
                    VF[e * 136 + xrow] = __builtin_bit_cast(short, (_Float16)vD[rr]);
            }
        }
        __syncthreads();

        // ---- (c): build QF rows from Y, 2 threads per row; t-word -> KF ----
        {
            const f4* xp = (const f4*)&XB[r * 12];
            f4 b0 = xp[0], b1 = xp[1], b2 = xp[2];
            float y[9] = {b0.x, b0.y, b0.z, b0.w, b1.x, b1.y, b1.z, b1.w, b2.x};
            const float tb = b2.y;          // t at XB col 9
            _Float16 H[9];
            #pragma unroll
            for (int e = 0; e < Dn; ++e) H[e] = (_Float16)y[e];
            u4v* qq = (u4v*)(QF + r * 40);
            if (!hi) {
                _Float16 l[6];
                #pragma unroll
                for (int e = 0; e < 6; ++e) l[e] = (_Float16)(y[e] - (float)H[e]);
                qq[0] = (u4v){ pk(H[0],H[1]), pk(H[2],H[3]), pk(H[4],H[5]), pk(H[6],H[7]) };
                qq[2] = (u4v){ pk(H[7],H[8]), pk(l[0],l[1]), pk(l[2],l[3]), pk(l[4],l[5]) };
            } else {
                const _Float16 l6 = (_Float16)(y[6] - (float)H[6]);
                const _Float16 l7 = (_Float16)(y[7] - (float)H[7]);
                const _Float16 l8 = (_Float16)(y[8] - (float)H[8]);
                qq[1] = (u4v){ pk(H[8],H[0]), pk(H[1],H[2]), pk(H[3],H[4]), pk(H[5],H[6]) };
                qq[3] = (u4v){ pk(l6,l7),     pk(l8,z0),     pk(one,one),   0u };
                const _Float16 th = (_Float16)tb;
                const _Float16 tl = (_Float16)(tb - (float)th);
                ((unsigned*)(KF + r * 40))[14] = pk(th, tl);   // slots 28,29
            }
        }
        __syncthreads();

        // ---- (d): attention (unchanged structure) ----
        h8 kfr[8];
        #pragma unroll
        for (int kt = 0; kt < 8; ++kt)
            kfr[kt] = read_quad(KF, kt * 16 + col, g);

        // V^T A-frags with permuted K-dim: slot (g,j) <-> key 16*(2s+(j>>2))+4g+(j&3)
        h8 vf[4];
        #pragma unroll
        for (int s = 0; s < 4; ++s) {
            const short* p0 = VF + col * 136 + 32 * s + 4 * g;
            s4v va = *(const s4v*)p0;
            s4v vb = *(const s4v*)(p0 + 16);
            vf[s] = __builtin_bit_cast(h8,
                __builtin_shufflevector(va, vb, 0, 1, 2, 3, 4, 5, 6, 7));
        }

        #pragma unroll
        for (int ti = 0; ti < 2; ++ti) {
            const int qt = 2 * wv + ti;
            const int q  = qt * 16 + col;
            h8 bq3 = read_quad(QF, q, g);

            f4 acc[8];
            #pragma unroll
            for (int kt = 0; kt < 8; ++kt)
                acc[kt] = __builtin_amdgcn_mfma_f32_16x16x32_f16(kfr[kt], bq3, (f4)(0.0f), 0, 0, 0);

            // lane holds S^T[key = kt*16 + 4g + rr][q] (log2 domain); exp2 direct.
            #pragma unroll
            for (int kt = 0; kt < 8; ++kt)
                #pragma unroll
                for (int rr = 0; rr < 4; ++rr)
                    acc[kt][rr] = __builtin_amdgcn_exp2f(acc[kt][rr]);

            // P B-frags: slot j=0..3 -> (kt=2s, rr=j); j=4..7 -> (kt=2s+1, rr=j&3)
            f4 oac = (f4)(0.0f);
            #pragma unroll
            for (int s = 0; s < 4; ++s) {
                u4v up = (u4v){
                    __builtin_bit_cast(unsigned, __builtin_amdgcn_cvt_pkrtz(acc[2*s][0],   acc[2*s][1])),
                    __builtin_bit_cast(unsigned, __builtin_amdgcn_cvt_pkrtz(acc[2*s][2],   acc[2*s][3])),
                    __builtin_bit_cast(unsigned, __builtin_amdgcn_cvt_pkrtz(acc[2*s+1][0], acc[2*s+1][1])),
                    __builtin_bit_cast(unsigned, __builtin_amdgcn_cvt_pkrtz(acc[2*s+1][2], acc[2*s+1][3])) };
                oac = __builtin_amdgcn_mfma_f32_16x16x32_f16(vf[s], __builtin_bit_cast(h8, up), oac, 0, 0, 0);
            }
            // denominator: O^T row 9 = sum_k P[k][q], held by lane 32+q, reg 1
            const float sm = __shfl(oac[1], 32 + col);
            const float rl = __builtin_amdgcn_rcpf(sm);
            oac *= rl;
            // O^T C-layout: lane col = q, rows d = 4g + rr; keep d < 12
            if (g < 3)
                *(f4*)&XB[q * 12 + g * 4] = oac;
        }
        __syncthreads();
    }

    // ---- logits + log_softmax ----
    if (!hi) {
        const f4* xp = (const f4*)&XB[r * 12];
        f4 a0 = xp[0], a1 = xp[1], a2 = xp[2];
        float xr[9] = {a0.x, a0.y, a0.z, a0.w, a1.x, a1.y, a1.z, a1.w, a2.x};
        float lg[Vn];
        #pragma unroll
        for (int v = 0; v < Vn; ++v) {
            float a = bout[v];
            #pragma unroll
            for (int d = 0; d < Dn; ++d) a = fmaf(xr[d], Wout[v * Dn + d], a);
            lg[v] = a;
        }
        float mm = lg[0];
        #pragma unroll
        for (int v = 1; v < Vn; ++v) mm = fmaxf(mm, lg[v]);
        float sum = 0.0f;
        #pragma unroll
        for (int v = 0; v < Vn; ++v)
            sum += __builtin_amdgcn_exp2f((lg[v] - mm) * 1.44269504f);
        const float lse = __builtin_amdgcn_logf(sum) * 0.69314718f + mm;
        float* op = out + ((size_t)b * Sn + r) * Vn;
        #pragma unroll
        for (int v = 0; v < Vn; ++v) op[v] = lg[v] - lse;
    }
}

extern "C" void kernel_launch(void* const* d_in, const int* in_sizes, int n_in,
                              void* d_out, int out_size, void* d_ws, size_t ws_size,
                              hipStream_t stream) {
    const int*   tokens = (const int*)  d_in[0];
    const float* emb    = (const float*)d_in[1];
    const float* Wq     = (const float*)d_in[2];
    const float* bq_    = (const float*)d_in[3];
    const float* Wk     = (const float*)d_in[4];
    const float* Wv     = (const float*)d_in[6];
    const float* bv_    = (const float*)d_in[7];
    const float* Wout   = (const float*)d_in[8];
    const float* bout_  = (const float*)d_in[9];
    float* out = (float*)d_out;
    float* ws  = (float*)d_ws;

    prep_kernel<<<dim3(6), dim3(256), 0, stream>>>(Wq, bq_, Wk, ws);
    prep2_kernel<<<dim3(16), dim3(256), 0, stream>>>(Wv, bv_, ws);
    bert_kernel<<<dim3(Bn), dim3(256), 0, stream>>>(
        tokens, emb, Wout, bout_, ws, out);
}